// Round 1
// baseline (247.187 us; speedup 1.0000x reference)
//
#include <hip/hip_runtime.h>
#include <hip/hip_bf16.h>

#define BB 32
#define NN 1024
#define QQ 64
#define HH 768

typedef __attribute__((ext_vector_type(8))) short short8;
typedef __attribute__((ext_vector_type(4))) float f32x4;

__device__ __forceinline__ unsigned short f2b(float f) {
  unsigned int u = __float_as_uint(f);
  unsigned int r = u + 0x7fffu + ((u >> 16) & 1u);
  return (unsigned short)(r >> 16);
}

// K0: qwB[b][q][h] = bf16(qc[b][q][h]*w_nq[h] + w_n[h]);  qcT[b][h][q] = bf16(qc[b][q][h])
__global__ void k_prep(const float* __restrict__ qc, const float* __restrict__ w,
                       unsigned short* __restrict__ qwB, unsigned short* __restrict__ qcT) {
  int idx = blockIdx.x * 256 + threadIdx.x;   // 0 .. B*Q*H-1
  int h = idx % HH;
  qwB[idx] = f2b(qc[idx] * w[2 * HH + h] + w[h]);
  int q2 = idx & 63;
  int h2 = (idx >> 6) % HH;
  int b2 = idx / (HH * QQ);
  qcT[idx] = f2b(qc[(b2 * QQ + q2) * HH + h2]);
}

// K0b: sq[b][q] = dot(qc[b][q][:], w_q)
__global__ void k_sq(const float* __restrict__ qc, const float* __restrict__ w,
                     float* __restrict__ sq) {
  int wid = (blockIdx.x * 256 + threadIdx.x) >> 6; // 0..2047  (b*64+q)
  int l = threadIdx.x & 63;
  const float* row = qc + (size_t)wid * HH;
  float s = 0.f;
#pragma unroll
  for (int i = 0; i < 12; ++i) s += row[i * 64 + l] * w[HH + i * 64 + l];
#pragma unroll
  for (int m = 1; m < 64; m <<= 1) s += __shfl_xor(s, m);
  if (l == 0) sq[wid] = s;
}

// K1: per block: batch b, 64-row tile. GEMM1 (sim) -> softmax -> GEMM2 (n2q) -> out chunks 0..2
__global__ __launch_bounds__(256) void k_main(
    const float* __restrict__ nc, const unsigned short* __restrict__ qwB,
    const unsigned short* __restrict__ qcT, const float* __restrict__ sq,
    float* __restrict__ rowmax_out, float* __restrict__ out)
{
  __shared__ unsigned short aLDS[64 * 128]; // 16 KB  (A tile / later qcT tile 128x64)
  __shared__ unsigned short bLDS[64 * 128]; // 16 KB  (B' tile [q][k])
  __shared__ unsigned short pLDS[64 * 64];  // 8 KB   (softmax probs, [n][q] bf16)

  const int tid = threadIdx.x;
  const int w = tid >> 6, l = tid & 63;
  const int l15 = l & 15, lg = l >> 4;
  const int b = blockIdx.x >> 4, tile = blockIdx.x & 15;
  const int row0 = tile * 64;

  const float* ncB = nc + (size_t)(b * NN + row0) * HH;
  const unsigned short* qwBb = qwB + (size_t)b * QQ * HH;

  f32x4 acc[4] = {};
  for (int kc = 0; kc < 6; ++kc) {
#pragma unroll
    for (int i = 0; i < 4; ++i) {
      int unit = i * 256 + tid;       // 1024 16B-units: 64 rows x 16
      int r = unit >> 4, uu = unit & 15;
      const float* src = ncB + r * HH + kc * 128 + uu * 8;
      float4 f0 = *(const float4*)src;
      float4 f1 = *(const float4*)(src + 4);
      short8 v;
      v[0] = (short)f2b(f0.x); v[1] = (short)f2b(f0.y);
      v[2] = (short)f2b(f0.z); v[3] = (short)f2b(f0.w);
      v[4] = (short)f2b(f1.x); v[5] = (short)f2b(f1.y);
      v[6] = (short)f2b(f1.z); v[7] = (short)f2b(f1.w);
      int off = r * 256 + ((uu * 16) ^ ((r & 7) << 4));
      *(short8*)((char*)aLDS + off) = v;
      short8 bv = *(const short8*)(qwBb + r * HH + kc * 128 + uu * 8);
      *(short8*)((char*)bLDS + off) = bv;
    }
    __syncthreads();
#pragma unroll
    for (int ks = 0; ks < 4; ++ks) {
      int kbyte = ks * 64 + lg * 16;
      int arow = w * 16 + l15;
      short8 af = *(short8*)((char*)aLDS + arow * 256 + (kbyte ^ ((l & 7) << 4)));
#pragma unroll
      for (int nt = 0; nt < 4; ++nt) {
        int brow = nt * 16 + l15;
        short8 bf = *(short8*)((char*)bLDS + brow * 256 + (kbyte ^ ((l & 7) << 4)));
        acc[nt] = __builtin_amdgcn_mfma_f32_16x16x32_bf16(af, bf, acc[nt], 0, 0, 0);
      }
    }
    __syncthreads();
  }

  // softmax over q (64) per row; D layout: row = w*16 + lg*4 + j, col q = nt*16 + l15
  float sqv[4];
#pragma unroll
  for (int nt = 0; nt < 4; ++nt) sqv[nt] = sq[b * QQ + nt * 16 + l15];
#pragma unroll
  for (int j = 0; j < 4; ++j) {
    float mm = -1e30f;
#pragma unroll
    for (int nt = 0; nt < 4; ++nt) { acc[nt][j] += sqv[nt]; mm = fmaxf(mm, acc[nt][j]); }
    mm = fmaxf(mm, __shfl_xor(mm, 1));
    mm = fmaxf(mm, __shfl_xor(mm, 2));
    mm = fmaxf(mm, __shfl_xor(mm, 4));
    mm = fmaxf(mm, __shfl_xor(mm, 8));
    float ss = 0.f;
#pragma unroll
    for (int nt = 0; nt < 4; ++nt) { float p = __expf(acc[nt][j] - mm); acc[nt][j] = p; ss += p; }
    ss += __shfl_xor(ss, 1); ss += __shfl_xor(ss, 2);
    ss += __shfl_xor(ss, 4); ss += __shfl_xor(ss, 8);
    float inv = 1.0f / ss;
    int r = w * 16 + lg * 4 + j;
#pragma unroll
    for (int nt = 0; nt < 4; ++nt)
      pLDS[r * 64 + nt * 16 + l15] = f2b(acc[nt][j] * inv);
    if (l15 == 0) rowmax_out[b * NN + row0 + r] = mm;
  }

  // GEMM2: n2q[64][768] = a[64][64] @ qc[64][768]; A-frags from own-wave pLDS rows
  short8 a2[2];
#pragma unroll
  for (int ks2 = 0; ks2 < 2; ++ks2)
    a2[ks2] = *(short8*)((char*)pLDS + (w * 16 + l15) * 128 + ks2 * 64 + lg * 16);

  const unsigned short* qcTb = qcT + (size_t)b * HH * QQ;
  for (int hc = 0; hc < 6; ++hc) {
#pragma unroll
    for (int i = 0; i < 4; ++i) {
      int unit = i * 256 + tid;     // 1024 units: 128 h-rows x 8
      int r = unit >> 3, uu = unit & 7;
      short8 v = *(const short8*)(qcTb + (size_t)(hc * 128 + r) * 64 + uu * 8);
      int off = r * 128 + ((uu * 16) ^ ((r & 7) << 4));
      *(short8*)((char*)aLDS + off) = v;
    }
    __syncthreads();
#pragma unroll
    for (int nt2 = 0; nt2 < 8; ++nt2) {
      f32x4 c2 = {};
#pragma unroll
      for (int ks2 = 0; ks2 < 2; ++ks2) {
        int hrow = nt2 * 16 + l15;
        int kbyte = ks2 * 64 + lg * 16;
        short8 bf = *(short8*)((char*)aLDS + hrow * 128 + (kbyte ^ ((l & 7) << 4)));
        c2 = __builtin_amdgcn_mfma_f32_16x16x32_bf16(a2[ks2], bf, c2, 0, 0, 0);
      }
#pragma unroll
      for (int j = 0; j < 4; ++j) {
        int r = w * 16 + lg * 4 + j;
        int h = hc * 128 + nt2 * 16 + l15;
        float n2 = c2[j];
        float ncv = ncB[r * HH + h];
        size_t ob = (size_t)(b * NN + row0 + r) * 3072 + h;
        out[ob] = ncv;
        out[ob + HH] = n2;
        out[ob + 2 * HH] = ncv * n2;
      }
    }
    __syncthreads();
  }
}

// K2: per (b, 128-row segment): redundant b-softmax stats, partial q2n via atomics
__global__ void k_q2n(const float* __restrict__ rowmax, const float* __restrict__ nc,
                      float* __restrict__ q2n) {
  int b = blockIdx.x >> 3, seg = blockIdx.x & 7;
  int t = threadIdx.x, w = t >> 6, l = t & 63;
  __shared__ float redm[4], reds[4];
  float v[4];
#pragma unroll
  for (int i = 0; i < 4; ++i) v[i] = rowmax[b * NN + i * 256 + t];
  float mx = fmaxf(fmaxf(v[0], v[1]), fmaxf(v[2], v[3]));
#pragma unroll
  for (int m = 1; m < 64; m <<= 1) mx = fmaxf(mx, __shfl_xor(mx, m));
  if (l == 0) redm[w] = mx;
  __syncthreads();
  mx = fmaxf(fmaxf(redm[0], redm[1]), fmaxf(redm[2], redm[3]));
  float ss = 0.f;
#pragma unroll
  for (int i = 0; i < 4; ++i) ss += __expf(v[i] - mx);
#pragma unroll
  for (int m = 1; m < 64; m <<= 1) ss += __shfl_xor(ss, m);
  if (l == 0) reds[w] = ss;
  __syncthreads();
  float rsm = 1.0f / (reds[0] + reds[1] + reds[2] + reds[3]);
  float a0 = 0.f, a1 = 0.f, a2 = 0.f;
  const float* base = nc + (size_t)b * NN * HH + t;
  for (int n = seg * 128; n < seg * 128 + 128; ++n) {
    float wv = __expf(rowmax[b * NN + n] - mx) * rsm;
    const float* p = base + (size_t)n * HH;
    a0 += wv * p[0]; a1 += wv * p[256]; a2 += wv * p[512];
  }
  atomicAdd(&q2n[b * HH + t], a0);
  atomicAdd(&q2n[b * HH + t + 256], a1);
  atomicAdd(&q2n[b * HH + t + 512], a2);
}

// K3: out chunk 3 = nc * q2n (broadcast over n)
__global__ void k_final(const float* __restrict__ nc, const float* __restrict__ q2n,
                        float* __restrict__ out) {
  size_t bn = blockIdx.x;        // 0..32767
  int b = (int)(bn >> 10);
  int t = threadIdx.x;           // 0..191
  float4 ncv = *(const float4*)(nc + bn * HH + t * 4);
  float4 qv = *(const float4*)(q2n + (size_t)b * HH + t * 4);
  float4 o;
  o.x = ncv.x * qv.x; o.y = ncv.y * qv.y; o.z = ncv.z * qv.z; o.w = ncv.w * qv.w;
  *(float4*)(out + bn * 3072 + 2304 + t * 4) = o;
}

extern "C" void kernel_launch(void* const* d_in, const int* in_sizes, int n_in,
                              void* d_out, int out_size, void* d_ws, size_t ws_size,
                              hipStream_t stream) {
  (void)in_sizes; (void)n_in; (void)out_size; (void)ws_size;
  const float* nc = (const float*)d_in[0];
  const float* qc = (const float*)d_in[1];
  const float* w  = (const float*)d_in[3];
  float* out = (float*)d_out;
  char* ws = (char*)d_ws;
  unsigned short* qwB = (unsigned short*)(ws);                 // 3,145,728 B (bf16 B*Q*H)
  unsigned short* qcT = (unsigned short*)(ws + 3145728);       // 3,145,728 B
  float* sqv    = (float*)(ws + 6291456);                      // 8 KB
  float* rowmax = (float*)(ws + 6299648);                      // 128 KB
  float* q2n    = (float*)(ws + 6430720);                      // 96 KB

  hipMemsetAsync(q2n, 0, BB * HH * sizeof(float), stream);
  k_prep<<<6144, 256, 0, stream>>>(qc, w, qwB, qcT);
  k_sq<<<512, 256, 0, stream>>>(qc, w, sqv);
  k_main<<<512, 256, 0, stream>>>(nc, qwB, qcT, sqv, rowmax, out);
  k_q2n<<<256, 256, 0, stream>>>(rowmax, nc, q2n);
  k_final<<<32768, 192, 0, stream>>>(nc, q2n, out);
}

// Round 2
// 199.109 us; speedup vs baseline: 1.2415x; 1.2415x over previous
//
#include <hip/hip_runtime.h>
#include <hip/hip_bf16.h>

#define BB 32
#define NN 1024
#define QQ 64
#define HH 768

typedef __attribute__((ext_vector_type(8))) short short8;
typedef __attribute__((ext_vector_type(4))) float f32x4;

__device__ __forceinline__ unsigned short f2b(float f) {
  unsigned int u = __float_as_uint(f);
  unsigned int r = u + 0x7fffu + ((u >> 16) & 1u);
  return (unsigned short)(r >> 16);
}

// K0: qwB[b][q][h] = bf16(qc[b][q][h]*w_nq[h] + w_n[h]);  qcT[b][h][q] = bf16(qc[b][q][h])
__global__ void k_prep(const float* __restrict__ qc, const float* __restrict__ w,
                       unsigned short* __restrict__ qwB, unsigned short* __restrict__ qcT) {
  int idx = blockIdx.x * 256 + threadIdx.x;   // 0 .. B*Q*H-1
  int h = idx % HH;
  qwB[idx] = f2b(qc[idx] * w[2 * HH + h] + w[h]);
  int q2 = idx & 63;
  int h2 = (idx >> 6) % HH;
  int b2 = idx / (HH * QQ);
  qcT[idx] = f2b(qc[(b2 * QQ + q2) * HH + h2]);
}

// K0b: sq[b][q] = dot(qc[b][q][:], w_q)
__global__ void k_sq(const float* __restrict__ qc, const float* __restrict__ w,
                     float* __restrict__ sq) {
  int wid = (blockIdx.x * 256 + threadIdx.x) >> 6; // 0..2047  (b*64+q)
  int l = threadIdx.x & 63;
  const float* row = qc + (size_t)wid * HH;
  float s = 0.f;
#pragma unroll
  for (int i = 0; i < 12; ++i) s += row[i * 64 + l] * w[HH + i * 64 + l];
#pragma unroll
  for (int m = 1; m < 64; m <<= 1) s += __shfl_xor(s, m);
  if (l == 0) sq[wid] = s;
}

// K1: per block: batch b, 64-row tile. GEMM1 -> softmax (+ per-tile q2n partials) ->
//     GEMM2 (operand-swapped: D[h][n] so threads own float4 in h) -> out chunks 0..2
__global__ __launch_bounds__(256) void k_main(
    const float* __restrict__ nc, const unsigned short* __restrict__ qwB,
    const unsigned short* __restrict__ qcT, const float* __restrict__ sq,
    float* __restrict__ partial, float* __restrict__ mtse, float* __restrict__ out)
{
  __shared__ char smem[40960];
  unsigned short* aLDS = (unsigned short*)smem;            // 16 KB (A tile / qcT tile)
  unsigned short* bLDS = (unsigned short*)(smem + 16384);  // 16 KB (B' tile; aliased later)
  unsigned short* pLDS = (unsigned short*)(smem + 32768);  // 8 KB (probs [n][q] bf16)
  float* rowmF = (float*)(smem + 16384);                   // 64 floats (aliases bLDS, post-GEMM1)
  float* wvF   = (float*)(smem + 16384 + 256);             // 64 floats

  const int tid = threadIdx.x;
  const int w = tid >> 6, l = tid & 63;
  const int l15 = l & 15, lg = l >> 4;
  const int b = blockIdx.x >> 4, tile = blockIdx.x & 15;
  const int row0 = tile * 64;

  const float* ncB = nc + (size_t)(b * NN + row0) * HH;
  const unsigned short* qwBb = qwB + (size_t)b * QQ * HH;

  // ---------------- GEMM1: sim[n][q] ----------------
  f32x4 acc[4] = {};
  for (int kc = 0; kc < 6; ++kc) {
#pragma unroll
    for (int i = 0; i < 4; ++i) {
      int unit = i * 256 + tid;       // 1024 16B-units: 64 rows x 16
      int r = unit >> 4, uu = unit & 15;
      const float* src = ncB + r * HH + kc * 128 + uu * 8;
      float4 f0 = *(const float4*)src;
      float4 f1 = *(const float4*)(src + 4);
      short8 v;
      v[0] = (short)f2b(f0.x); v[1] = (short)f2b(f0.y);
      v[2] = (short)f2b(f0.z); v[3] = (short)f2b(f0.w);
      v[4] = (short)f2b(f1.x); v[5] = (short)f2b(f1.y);
      v[6] = (short)f2b(f1.z); v[7] = (short)f2b(f1.w);
      int off = r * 256 + ((uu * 16) ^ ((r & 7) << 4));
      *(short8*)((char*)aLDS + off) = v;
      short8 bv = *(const short8*)(qwBb + r * HH + kc * 128 + uu * 8);
      *(short8*)((char*)bLDS + off) = bv;
    }
    __syncthreads();
#pragma unroll
    for (int ks = 0; ks < 4; ++ks) {
      int kbyte = ks * 64 + lg * 16;
      int arow = w * 16 + l15;
      short8 af = *(short8*)((char*)aLDS + arow * 256 + (kbyte ^ ((l & 7) << 4)));
#pragma unroll
      for (int nt = 0; nt < 4; ++nt) {
        int brow = nt * 16 + l15;
        short8 bf = *(short8*)((char*)bLDS + brow * 256 + (kbyte ^ ((l & 7) << 4)));
        acc[nt] = __builtin_amdgcn_mfma_f32_16x16x32_bf16(af, bf, acc[nt], 0, 0, 0);
      }
      __asm__ volatile("" ::: "memory");
    }
    __syncthreads();
  }

  // ---------------- softmax over q; D layout: row n = w*16+lg*4+j, col q = nt*16+l15 ----
  float sqv[4];
#pragma unroll
  for (int nt = 0; nt < 4; ++nt) sqv[nt] = sq[b * QQ + nt * 16 + l15];
#pragma unroll
  for (int j = 0; j < 4; ++j) {
    float mm = -1e30f;
#pragma unroll
    for (int nt = 0; nt < 4; ++nt) { acc[nt][j] += sqv[nt]; mm = fmaxf(mm, acc[nt][j]); }
    mm = fmaxf(mm, __shfl_xor(mm, 1));
    mm = fmaxf(mm, __shfl_xor(mm, 2));
    mm = fmaxf(mm, __shfl_xor(mm, 4));
    mm = fmaxf(mm, __shfl_xor(mm, 8));
    float ss = 0.f;
#pragma unroll
    for (int nt = 0; nt < 4; ++nt) { float p = __expf(acc[nt][j] - mm); acc[nt][j] = p; ss += p; }
    ss += __shfl_xor(ss, 1); ss += __shfl_xor(ss, 2);
    ss += __shfl_xor(ss, 4); ss += __shfl_xor(ss, 8);
    float inv = 1.0f / ss;
    int r = w * 16 + lg * 4 + j;
#pragma unroll
    for (int nt = 0; nt < 4; ++nt)
      pLDS[r * 64 + nt * 16 + l15] = f2b(acc[nt][j] * inv);
    if (l15 == 0) rowmF[r] = mm;   // aliases bLDS; safe after GEMM1's trailing sync
  }
  __syncthreads();

  // ---------------- per-tile q2n partials (tile is L2/L3-hot) ----------------
  float m_t = -1e30f;
#pragma unroll
  for (int i = 0; i < 16; ++i) {
    f32x4 v = ((f32x4*)rowmF)[i];
    m_t = fmaxf(m_t, fmaxf(fmaxf(v[0], v[1]), fmaxf(v[2], v[3])));
  }
  if (tid < 64) wvF[tid] = __expf(rowmF[tid] - m_t);
  __syncthreads();
  {
    float sv = wvF[l];
#pragma unroll
    for (int m = 1; m < 64; m <<= 1) sv += __shfl_xor(sv, m);
    if (tid == 0) {
      mtse[(b * 16 + tile) * 2] = m_t;
      mtse[(b * 16 + tile) * 2 + 1] = sv;
    }
  }
  {
    float p0 = 0.f, p1 = 0.f, p2 = 0.f;
    for (int n = 0; n < 64; ++n) {
      float wv = wvF[n];
      const float* pr = ncB + n * HH + tid;
      p0 += wv * pr[0]; p1 += wv * pr[256]; p2 += wv * pr[512];
    }
    float* pp = partial + (size_t)(b * 16 + tile) * HH + tid;
    pp[0] = p0; pp[256] = p1; pp[512] = p2;
  }

  // ---------------- GEMM2 (swapped): D[h][n] = qcT . probs ----------------
  short8 a2[2];
#pragma unroll
  for (int ks2 = 0; ks2 < 2; ++ks2)
    a2[ks2] = *(short8*)((char*)pLDS + (w * 16 + l15) * 128 + ks2 * 64 + lg * 16);

  const unsigned short* qcTb = qcT + (size_t)b * HH * QQ;
  const float* ncrow = nc + (size_t)(b * NN + row0 + w * 16 + l15) * HH;
  float* orow = out + (size_t)(b * NN + row0 + w * 16 + l15) * 3072;

  for (int hc = 0; hc < 6; ++hc) {
#pragma unroll
    for (int i = 0; i < 4; ++i) {
      int unit = i * 256 + tid;     // 1024 units: 128 h-rows x 8
      int r = unit >> 3, uu = unit & 7;
      short8 v = *(const short8*)(qcTb + (size_t)(hc * 128 + r) * 64 + uu * 8);
      int off = r * 128 + ((uu * 16) ^ ((r & 7) << 4));
      *(short8*)((char*)aLDS + off) = v;
    }
    __syncthreads();
#pragma unroll
    for (int hg = 0; hg < 8; ++hg) {
      f32x4 c2 = {};
#pragma unroll
      for (int ks2 = 0; ks2 < 2; ++ks2) {
        int hrow = hg * 16 + l15;
        int kbyte = ks2 * 64 + lg * 16;
        short8 hf = *(short8*)((char*)aLDS + hrow * 128 + (kbyte ^ ((l & 7) << 4)));
        c2 = __builtin_amdgcn_mfma_f32_16x16x32_bf16(hf, a2[ks2], c2, 0, 0, 0);
      }
      // thread owns n = w*16+l15 (row), h = hc*128 + hg*16 + lg*4 + (0..3)
      int hbase = hc * 128 + hg * 16 + lg * 4;
      f32x4 ncv = *(const f32x4*)(ncrow + hbase);
      f32x4 prod = ncv * c2;
      __builtin_nontemporal_store(ncv,  (f32x4*)(orow + hbase));
      __builtin_nontemporal_store(c2,   (f32x4*)(orow + HH + hbase));
      __builtin_nontemporal_store(prod, (f32x4*)(orow + 2 * HH + hbase));
    }
    __syncthreads();
  }
}

// K2: combine per-tile partials -> q2n[b][h]   (32 blocks, trivial traffic)
__global__ void k_comb(const float* __restrict__ partial, const float* __restrict__ mtse,
                       float* __restrict__ q2n) {
  int b = blockIdx.x, t = threadIdx.x;
  float mt[16], se[16];
  float M = -1e30f;
#pragma unroll
  for (int i = 0; i < 16; ++i) {
    mt[i] = mtse[(b * 16 + i) * 2];
    se[i] = mtse[(b * 16 + i) * 2 + 1];
    M = fmaxf(M, mt[i]);
  }
  float denom = 0.f;
#pragma unroll
  for (int i = 0; i < 16; ++i) { mt[i] = __expf(mt[i] - M); denom += mt[i] * se[i]; }
  float inv = 1.0f / denom;
  float a0 = 0.f, a1 = 0.f, a2 = 0.f;
#pragma unroll
  for (int i = 0; i < 16; ++i) {
    const float* pp = partial + (size_t)(b * 16 + i) * HH + t;
    float c = mt[i] * inv;
    a0 += c * pp[0]; a1 += c * pp[256]; a2 += c * pp[512];
  }
  q2n[b * HH + t] = a0;
  q2n[b * HH + t + 256] = a1;
  q2n[b * HH + t + 512] = a2;
}

// K3: out chunk 3 = nc * q2n (broadcast over n)
__global__ void k_final(const float* __restrict__ nc, const float* __restrict__ q2n,
                        float* __restrict__ out) {
  size_t bn = blockIdx.x;        // 0..32767
  int b = (int)(bn >> 10);
  int t = threadIdx.x;           // 0..191
  f32x4 ncv = *(const f32x4*)(nc + bn * HH + t * 4);
  f32x4 qv = *(const f32x4*)(q2n + (size_t)b * HH + t * 4);
  f32x4 o = ncv * qv;
  __builtin_nontemporal_store(o, (f32x4*)(out + bn * 3072 + 2304 + t * 4));
}

extern "C" void kernel_launch(void* const* d_in, const int* in_sizes, int n_in,
                              void* d_out, int out_size, void* d_ws, size_t ws_size,
                              hipStream_t stream) {
  (void)in_sizes; (void)n_in; (void)out_size; (void)ws_size;
  const float* nc = (const float*)d_in[0];
  const float* qc = (const float*)d_in[1];
  const float* w  = (const float*)d_in[3];
  float* out = (float*)d_out;
  char* ws = (char*)d_ws;
  unsigned short* qwB = (unsigned short*)(ws);                 // 3,145,728 B
  unsigned short* qcT = (unsigned short*)(ws + 3145728);       // 3,145,728 B
  float* sqv     = (float*)(ws + 6291456);                     // 8 KB
  float* partial = (float*)(ws + 6299648);                     // 1,572,864 B
  float* mtse    = (float*)(ws + 7872512);                     // 4 KB
  float* q2n     = (float*)(ws + 7876608);                     // 96 KB

  k_prep<<<6144, 256, 0, stream>>>(qc, w, qwB, qcT);
  k_sq<<<512, 256, 0, stream>>>(qc, w, sqv);
  k_main<<<512, 256, 0, stream>>>(nc, qwB, qcT, sqv, partial, mtse, out);
  k_comb<<<32, 256, 0, stream>>>(partial, mtse, q2n);
  k_final<<<32768, 192, 0, stream>>>(nc, q2n, out);
}

// Round 3
// 188.771 us; speedup vs baseline: 1.3095x; 1.0548x over previous
//
#include <hip/hip_runtime.h>
#include <hip/hip_bf16.h>

#define BB 32
#define NN 1024
#define QQ 64
#define HH 768

typedef __attribute__((ext_vector_type(8))) short short8;
typedef __attribute__((ext_vector_type(4))) float f32x4;

__device__ __forceinline__ unsigned short f2b(float f) {
  unsigned int u = __float_as_uint(f);
  unsigned int r = u + 0x7fffu + ((u >> 16) & 1u);
  return (unsigned short)(r >> 16);
}

// K0 fused: blocks [0,6144): qwB + qcT; blocks [6144,6656): sq
__global__ void k_prep(const float* __restrict__ qc, const float* __restrict__ w,
                       unsigned short* __restrict__ qwB, unsigned short* __restrict__ qcT,
                       float* __restrict__ sq) {
  int bid = blockIdx.x;
  if (bid < 6144) {
    int idx = bid * 256 + threadIdx.x;   // 0 .. B*Q*H-1
    int h = idx % HH;
    qwB[idx] = f2b(qc[idx] * w[2 * HH + h] + w[h]);
    int q2 = idx & 63;
    int h2 = (idx >> 6) % HH;
    int b2 = idx / (HH * QQ);
    qcT[idx] = f2b(qc[(b2 * QQ + q2) * HH + h2]);
  } else {
    int wid = ((bid - 6144) * 256 + threadIdx.x) >> 6; // 0..2047  (b*64+q)
    int l = threadIdx.x & 63;
    const float* row = qc + (size_t)wid * HH;
    float s = 0.f;
#pragma unroll
    for (int i = 0; i < 12; ++i) s += row[i * 64 + l] * w[HH + i * 64 + l];
#pragma unroll
    for (int m = 1; m < 64; m <<= 1) s += __shfl_xor(s, m);
    if (l == 0) sq[wid] = s;
  }
}

// K1: GEMM1 (sim) -> softmax -> probs(bf16)->ws, per-tile q2n partials + (m_t, sumexp)
__global__ __launch_bounds__(256) void k_sim(
    const float* __restrict__ nc, const unsigned short* __restrict__ qwB,
    const float* __restrict__ sq, float* __restrict__ partial,
    float* __restrict__ mtse, unsigned short* __restrict__ probs)
{
  __shared__ char smem[32768];
  unsigned short* aLDS = (unsigned short*)smem;            // 16 KB (A tile)
  unsigned short* bLDS = (unsigned short*)(smem + 16384);  // 16 KB (B' tile)
  float* rowmF = (float*)(smem + 16384);                   // aliases bLDS, post-GEMM1
  float* wvF   = (float*)(smem + 16384 + 256);

  const int tid = threadIdx.x;
  const int w = tid >> 6, l = tid & 63;
  const int l15 = l & 15, lg = l >> 4;
  const int b = blockIdx.x >> 4, tile = blockIdx.x & 15;
  const int row0 = tile * 64;

  const float* ncB = nc + (size_t)(b * NN + row0) * HH;
  const unsigned short* qwBb = qwB + (size_t)b * QQ * HH;

  // ---------------- GEMM1: sim[n][q] ----------------
  f32x4 acc[4] = {};
  for (int kc = 0; kc < 6; ++kc) {
#pragma unroll
    for (int i = 0; i < 4; ++i) {
      int unit = i * 256 + tid;       // 1024 16B-units: 64 rows x 16
      int r = unit >> 4, uu = unit & 15;
      const float* src = ncB + r * HH + kc * 128 + uu * 8;
      float4 f0 = *(const float4*)src;
      float4 f1 = *(const float4*)(src + 4);
      short8 v;
      v[0] = (short)f2b(f0.x); v[1] = (short)f2b(f0.y);
      v[2] = (short)f2b(f0.z); v[3] = (short)f2b(f0.w);
      v[4] = (short)f2b(f1.x); v[5] = (short)f2b(f1.y);
      v[6] = (short)f2b(f1.z); v[7] = (short)f2b(f1.w);
      int off = r * 256 + ((uu * 16) ^ ((r & 7) << 4));
      *(short8*)((char*)aLDS + off) = v;
      short8 bv = *(const short8*)(qwBb + r * HH + kc * 128 + uu * 8);
      *(short8*)((char*)bLDS + off) = bv;
    }
    __syncthreads();
#pragma unroll
    for (int ks = 0; ks < 4; ++ks) {
      int kbyte = ks * 64 + lg * 16;
      int arow = w * 16 + l15;
      short8 af = *(short8*)((char*)aLDS + arow * 256 + (kbyte ^ ((l & 7) << 4)));
#pragma unroll
      for (int nt = 0; nt < 4; ++nt) {
        int brow = nt * 16 + l15;
        short8 bf = *(short8*)((char*)bLDS + brow * 256 + (kbyte ^ ((l & 7) << 4)));
        acc[nt] = __builtin_amdgcn_mfma_f32_16x16x32_bf16(af, bf, acc[nt], 0, 0, 0);
      }
      __asm__ volatile("" ::: "memory");
    }
    __syncthreads();
  }

  // ---------------- softmax over q; D layout: row n = w*16+lg*4+j, col q = nt*16+l15 ----
  unsigned short* pT = probs + (size_t)(b * 16 + tile) * (QQ * QQ);
  float sqv[4];
#pragma unroll
  for (int nt = 0; nt < 4; ++nt) sqv[nt] = sq[b * QQ + nt * 16 + l15];
#pragma unroll
  for (int j = 0; j < 4; ++j) {
    float mm = -1e30f;
#pragma unroll
    for (int nt = 0; nt < 4; ++nt) { acc[nt][j] += sqv[nt]; mm = fmaxf(mm, acc[nt][j]); }
    mm = fmaxf(mm, __shfl_xor(mm, 1));
    mm = fmaxf(mm, __shfl_xor(mm, 2));
    mm = fmaxf(mm, __shfl_xor(mm, 4));
    mm = fmaxf(mm, __shfl_xor(mm, 8));
    float ss = 0.f;
#pragma unroll
    for (int nt = 0; nt < 4; ++nt) { float p = __expf(acc[nt][j] - mm); acc[nt][j] = p; ss += p; }
    ss += __shfl_xor(ss, 1); ss += __shfl_xor(ss, 2);
    ss += __shfl_xor(ss, 4); ss += __shfl_xor(ss, 8);
    float inv = 1.0f / ss;
    int r = w * 16 + lg * 4 + j;
#pragma unroll
    for (int nt = 0; nt < 4; ++nt)
      pT[r * 64 + nt * 16 + l15] = f2b(acc[nt][j] * inv);
    if (l15 == 0) rowmF[r] = mm;   // aliases bLDS; safe after GEMM1's trailing sync
  }
  __syncthreads();

  // ---------------- per-tile q2n partials (tile rows L2-hot) ----------------
  float m_t = -1e30f;
#pragma unroll
  for (int i = 0; i < 16; ++i) {
    f32x4 v = ((f32x4*)rowmF)[i];
    m_t = fmaxf(m_t, fmaxf(fmaxf(v[0], v[1]), fmaxf(v[2], v[3])));
  }
  if (tid < 64) wvF[tid] = __expf(rowmF[tid] - m_t);
  __syncthreads();
  {
    float sv = wvF[l];
#pragma unroll
    for (int m = 1; m < 64; m <<= 1) sv += __shfl_xor(sv, m);
    if (tid == 0) {
      mtse[(b * 16 + tile) * 2] = m_t;
      mtse[(b * 16 + tile) * 2 + 1] = sv;
    }
  }
  {
    float p0 = 0.f, p1 = 0.f, p2 = 0.f;
    for (int n = 0; n < 64; ++n) {
      float wv = wvF[n];
      const float* pr = ncB + n * HH + tid;
      p0 += wv * pr[0]; p1 += wv * pr[256]; p2 += wv * pr[512];
    }
    float* pp = partial + (size_t)(b * 16 + tile) * HH + tid;
    pp[0] = p0; pp[256] = p1; pp[512] = p2;
  }
}

// K2: combine per-tile partials -> q2n[b][h]   (32 blocks, trivial traffic)
__global__ void k_comb(const float* __restrict__ partial, const float* __restrict__ mtse,
                       float* __restrict__ q2n) {
  int b = blockIdx.x, t = threadIdx.x;
  float mt[16], se[16];
  float M = -1e30f;
#pragma unroll
  for (int i = 0; i < 16; ++i) {
    mt[i] = mtse[(b * 16 + i) * 2];
    se[i] = mtse[(b * 16 + i) * 2 + 1];
    M = fmaxf(M, mt[i]);
  }
  float denom = 0.f;
#pragma unroll
  for (int i = 0; i < 16; ++i) { mt[i] = __expf(mt[i] - M); denom += mt[i] * se[i]; }
  float inv = 1.0f / denom;
  float a0 = 0.f, a1 = 0.f, a2 = 0.f;
#pragma unroll
  for (int i = 0; i < 16; ++i) {
    const float* pp = partial + (size_t)(b * 16 + i) * HH + t;
    float c = mt[i] * inv;
    a0 += c * pp[0]; a1 += c * pp[256]; a2 += c * pp[512];
  }
  q2n[b * HH + t] = a0;
  q2n[b * HH + t + 256] = a1;
  q2n[b * HH + t + 512] = a2;
}

// K3: GEMM2 (swapped: D[h][n]) + all four output chunks. Grid: (b, tile, h-half).
__global__ __launch_bounds__(256) void k_out(
    const float* __restrict__ nc, const unsigned short* __restrict__ qcT,
    const unsigned short* __restrict__ probs, const float* __restrict__ q2n,
    float* __restrict__ out)
{
  __shared__ char smem[16384];   // qcT chunk [128 h][64 q] bf16, XOR-swizzled

  const int tid = threadIdx.x;
  const int w = tid >> 6, l = tid & 63;
  const int l15 = l & 15, lg = l >> 4;
  const int b = blockIdx.x >> 5;
  const int tile = (blockIdx.x >> 1) & 15;
  const int hh = blockIdx.x & 1;
  const int row0 = tile * 64;

  // A-frags (probs, pre-normalized bf16) direct from global (L3-hot, 2x16B/thread)
  const unsigned short* pT = probs + (size_t)(b * 16 + tile) * (QQ * QQ);
  short8 a2[2];
  a2[0] = *(const short8*)((const char*)pT + (w * 16 + l15) * 128 + 0 * 64 + lg * 16);
  a2[1] = *(const short8*)((const char*)pT + (w * 16 + l15) * 128 + 1 * 64 + lg * 16);

  const unsigned short* qcTb = qcT + (size_t)b * HH * QQ;
  const int n = w * 16 + l15;
  const float* ncrow = nc + (size_t)(b * NN + row0 + n) * HH;
  float* orow = out + (size_t)(b * NN + row0 + n) * 3072;
  const float* q2nb = q2n + b * HH;

  for (int hc = hh * 3; hc < hh * 3 + 3; ++hc) {
#pragma unroll
    for (int i = 0; i < 4; ++i) {
      int unit = i * 256 + tid;     // 1024 units: 128 h-rows x 8
      int r = unit >> 3, uu = unit & 7;
      short8 v = *(const short8*)(qcTb + (size_t)(hc * 128 + r) * 64 + uu * 8);
      int off = r * 128 + ((uu * 16) ^ ((r & 7) << 4));
      *(short8*)(smem + off) = v;
    }
    __syncthreads();
#pragma unroll
    for (int hg = 0; hg < 8; ++hg) {
      f32x4 c2 = {};
#pragma unroll
      for (int ks2 = 0; ks2 < 2; ++ks2) {
        int hrow = hg * 16 + l15;
        int kbyte = ks2 * 64 + lg * 16;
        short8 hf = *(short8*)(smem + hrow * 128 + (kbyte ^ ((l & 7) << 4)));
        c2 = __builtin_amdgcn_mfma_f32_16x16x32_bf16(hf, a2[ks2], c2, 0, 0, 0);
      }
      // thread owns n = w*16+l15, h = hc*128 + hg*16 + lg*4 + (0..3)
      int hbase = hc * 128 + hg * 16 + lg * 4;
      f32x4 ncv = *(const f32x4*)(ncrow + hbase);
      f32x4 qv  = *(const f32x4*)(q2nb + hbase);
      __builtin_nontemporal_store(ncv,       (f32x4*)(orow + hbase));
      __builtin_nontemporal_store(c2,        (f32x4*)(orow + HH + hbase));
      __builtin_nontemporal_store(ncv * c2,  (f32x4*)(orow + 2 * HH + hbase));
      __builtin_nontemporal_store(ncv * qv,  (f32x4*)(orow + 2304 + hbase));
    }
    __syncthreads();
  }
}

extern "C" void kernel_launch(void* const* d_in, const int* in_sizes, int n_in,
                              void* d_out, int out_size, void* d_ws, size_t ws_size,
                              hipStream_t stream) {
  (void)in_sizes; (void)n_in; (void)out_size; (void)ws_size;
  const float* nc = (const float*)d_in[0];
  const float* qc = (const float*)d_in[1];
  const float* w  = (const float*)d_in[3];
  float* out = (float*)d_out;
  char* ws = (char*)d_ws;
  unsigned short* qwB = (unsigned short*)(ws);                 // 3,145,728 B
  unsigned short* qcT = (unsigned short*)(ws + 3145728);       // 3,145,728 B
  float* sqv     = (float*)(ws + 6291456);                     // 8 KB
  float* partial = (float*)(ws + 6299648);                     // 1,572,864 B
  float* mtse    = (float*)(ws + 7872512);                     // 4 KB
  float* q2n     = (float*)(ws + 7876608);                     // 96 KB
  unsigned short* probs = (unsigned short*)(ws + 7975424);     // 4,194,304 B

  k_prep<<<6656, 256, 0, stream>>>(qc, w, qwB, qcT, sqv);
  k_sim<<<512, 256, 0, stream>>>(nc, qwB, sqv, partial, mtse, probs);
  k_comb<<<32, 256, 0, stream>>>(partial, mtse, q2n);
  k_out<<<1024, 256, 0, stream>>>(nc, qcT, probs, q2n, out);
}

// Round 4
// 179.372 us; speedup vs baseline: 1.3781x; 1.0524x over previous
//
#include <hip/hip_runtime.h>
#include <hip/hip_bf16.h>

#define BB 32
#define NN 1024
#define QQ 64
#define HH 768

typedef __attribute__((ext_vector_type(8))) short short8;
typedef __attribute__((ext_vector_type(4))) float f32x4;

__device__ __forceinline__ unsigned short f2b(float f) {
  unsigned int u = __float_as_uint(f);
  unsigned int r = u + 0x7fffu + ((u >> 16) & 1u);
  return (unsigned short)(r >> 16);
}

// K0: blocks [0,6144): qcT transpose; blocks [6144,6656): sq
__global__ void k_prep(const float* __restrict__ qc, const float* __restrict__ w,
                       unsigned short* __restrict__ qcT, float* __restrict__ sq) {
  int bid = blockIdx.x;
  if (bid < 6144) {
    int idx = bid * 256 + threadIdx.x;   // 0 .. B*H*Q-1
    int q2 = idx & 63;
    int h2 = (idx >> 6) % HH;
    int b2 = idx / (HH * QQ);
    qcT[idx] = f2b(qc[(b2 * QQ + q2) * HH + h2]);
  } else {
    int wid = ((bid - 6144) * 256 + threadIdx.x) >> 6; // 0..2047  (b*64+q)
    int l = threadIdx.x & 63;
    const float* row = qc + (size_t)wid * HH;
    float s = 0.f;
#pragma unroll
    for (int i = 0; i < 12; ++i) s += row[i * 64 + l] * w[HH + i * 64 + l];
#pragma unroll
    for (int m = 1; m < 64; m <<= 1) s += __shfl_xor(s, m);
    if (l == 0) sq[wid] = s;
  }
}

// K1: GEMM1 (sim) -> softmax -> probs(bf16)->ws, per-tile q2n partials + (m_t, sumexp)
// B' = bf16(qc*w_nq + w_n) computed inline during staging (no prep pass needed).
__global__ __launch_bounds__(256) void k_sim(
    const float* __restrict__ nc, const float* __restrict__ qc,
    const float* __restrict__ w, const float* __restrict__ sq,
    float* __restrict__ partial, float* __restrict__ mtse,
    unsigned short* __restrict__ probs)
{
  __shared__ char smem[32768];
  unsigned short* aLDS = (unsigned short*)smem;            // 16 KB (A tile)
  unsigned short* bLDS = (unsigned short*)(smem + 16384);  // 16 KB (B' tile)
  float* rowmF = (float*)(smem + 16384);                   // aliases bLDS, post-GEMM1
  float* wvF   = (float*)(smem + 16384 + 256);

  const int tid = threadIdx.x;
  const int wv_ = tid >> 6, l = tid & 63;
  const int l15 = l & 15, lg = l >> 4;
  const int b = blockIdx.x >> 4, tile = blockIdx.x & 15;
  const int row0 = tile * 64;

  const float* ncB = nc + (size_t)(b * NN + row0) * HH;
  const float* qcB = qc + (size_t)b * QQ * HH;

  // ---------------- GEMM1: sim[n][q] ----------------
  f32x4 acc[4] = {};
  for (int kc = 0; kc < 6; ++kc) {
#pragma unroll
    for (int i = 0; i < 4; ++i) {
      int unit = i * 256 + tid;       // 1024 16B-units: 64 rows x 16
      int r = unit >> 4, uu = unit & 15;
      int h = kc * 128 + uu * 8;
      const float* src = ncB + r * HH + h;
      float4 f0 = *(const float4*)src;
      float4 f1 = *(const float4*)(src + 4);
      short8 v;
      v[0] = (short)f2b(f0.x); v[1] = (short)f2b(f0.y);
      v[2] = (short)f2b(f0.z); v[3] = (short)f2b(f0.w);
      v[4] = (short)f2b(f1.x); v[5] = (short)f2b(f1.y);
      v[6] = (short)f2b(f1.z); v[7] = (short)f2b(f1.w);
      int off = r * 256 + ((uu * 16) ^ ((r & 7) << 4));
      *(short8*)((char*)aLDS + off) = v;
      const float* qsrc = qcB + r * HH + h;
      float4 g0 = *(const float4*)qsrc;
      float4 g1 = *(const float4*)(qsrc + 4);
      float4 wn0 = *(const float4*)(w + h);
      float4 wn1 = *(const float4*)(w + h + 4);
      float4 wm0 = *(const float4*)(w + 2 * HH + h);
      float4 wm1 = *(const float4*)(w + 2 * HH + h + 4);
      short8 bv;
      bv[0] = (short)f2b(g0.x * wm0.x + wn0.x); bv[1] = (short)f2b(g0.y * wm0.y + wn0.y);
      bv[2] = (short)f2b(g0.z * wm0.z + wn0.z); bv[3] = (short)f2b(g0.w * wm0.w + wn0.w);
      bv[4] = (short)f2b(g1.x * wm1.x + wn1.x); bv[5] = (short)f2b(g1.y * wm1.y + wn1.y);
      bv[6] = (short)f2b(g1.z * wm1.z + wn1.z); bv[7] = (short)f2b(g1.w * wm1.w + wn1.w);
      *(short8*)((char*)bLDS + off) = bv;
    }
    __syncthreads();
#pragma unroll
    for (int ks = 0; ks < 4; ++ks) {
      int kbyte = ks * 64 + lg * 16;
      int arow = wv_ * 16 + l15;
      short8 af = *(short8*)((char*)aLDS + arow * 256 + (kbyte ^ ((l & 7) << 4)));
#pragma unroll
      for (int nt = 0; nt < 4; ++nt) {
        int brow = nt * 16 + l15;
        short8 bf = *(short8*)((char*)bLDS + brow * 256 + (kbyte ^ ((l & 7) << 4)));
        acc[nt] = __builtin_amdgcn_mfma_f32_16x16x32_bf16(af, bf, acc[nt], 0, 0, 0);
      }
      __asm__ volatile("" ::: "memory");
    }
    __syncthreads();
  }

  // ---------------- softmax over q; D layout: row n = w*16+lg*4+j, col q = nt*16+l15 ----
  unsigned short* pT = probs + (size_t)(b * 16 + tile) * (QQ * QQ);
  float sqv[4];
#pragma unroll
  for (int nt = 0; nt < 4; ++nt) sqv[nt] = sq[b * QQ + nt * 16 + l15];
#pragma unroll
  for (int j = 0; j < 4; ++j) {
    float mm = -1e30f;
#pragma unroll
    for (int nt = 0; nt < 4; ++nt) { acc[nt][j] += sqv[nt]; mm = fmaxf(mm, acc[nt][j]); }
    mm = fmaxf(mm, __shfl_xor(mm, 1));
    mm = fmaxf(mm, __shfl_xor(mm, 2));
    mm = fmaxf(mm, __shfl_xor(mm, 4));
    mm = fmaxf(mm, __shfl_xor(mm, 8));
    float ss = 0.f;
#pragma unroll
    for (int nt = 0; nt < 4; ++nt) { float p = __expf(acc[nt][j] - mm); acc[nt][j] = p; ss += p; }
    ss += __shfl_xor(ss, 1); ss += __shfl_xor(ss, 2);
    ss += __shfl_xor(ss, 4); ss += __shfl_xor(ss, 8);
    float inv = 1.0f / ss;
    int r = wv_ * 16 + lg * 4 + j;
#pragma unroll
    for (int nt = 0; nt < 4; ++nt)
      pT[r * 64 + nt * 16 + l15] = f2b(acc[nt][j] * inv);
    if (l15 == 0) rowmF[r] = mm;   // aliases bLDS; safe after GEMM1's trailing sync
  }
  __syncthreads();

  // ---------------- per-tile q2n partials (tile rows L2-hot) ----------------
  float m_t = -1e30f;
#pragma unroll
  for (int i = 0; i < 16; ++i) {
    f32x4 v = ((f32x4*)rowmF)[i];
    m_t = fmaxf(m_t, fmaxf(fmaxf(v[0], v[1]), fmaxf(v[2], v[3])));
  }
  if (tid < 64) wvF[tid] = __expf(rowmF[tid] - m_t);
  __syncthreads();
  {
    float sv = wvF[l];
#pragma unroll
    for (int m = 1; m < 64; m <<= 1) sv += __shfl_xor(sv, m);
    if (tid == 0) {
      mtse[(b * 16 + tile) * 2] = m_t;
      mtse[(b * 16 + tile) * 2 + 1] = sv;
    }
  }
  {
    float p0 = 0.f, p1 = 0.f, p2 = 0.f;
    for (int n = 0; n < 64; ++n) {
      float wvv = wvF[n];
      const float* pr = ncB + n * HH + tid;
      p0 += wvv * pr[0]; p1 += wvv * pr[256]; p2 += wvv * pr[512];
    }
    float* pp = partial + (size_t)(b * 16 + tile) * HH + tid;
    pp[0] = p0; pp[256] = p1; pp[512] = p2;
  }
}

// K2: combine per-tile partials -> q2n[b][h]   (32 blocks, trivial traffic)
__global__ void k_comb(const float* __restrict__ partial, const float* __restrict__ mtse,
                       float* __restrict__ q2n) {
  int b = blockIdx.x, t = threadIdx.x;
  float mt[16], se[16];
  float M = -1e30f;
#pragma unroll
  for (int i = 0; i < 16; ++i) {
    mt[i] = mtse[(b * 16 + i) * 2];
    se[i] = mtse[(b * 16 + i) * 2 + 1];
    M = fmaxf(M, mt[i]);
  }
  float denom = 0.f;
#pragma unroll
  for (int i = 0; i < 16; ++i) { mt[i] = __expf(mt[i] - M); denom += mt[i] * se[i]; }
  float inv = 1.0f / denom;
  float a0 = 0.f, a1 = 0.f, a2 = 0.f;
#pragma unroll
  for (int i = 0; i < 16; ++i) {
    const float* pp = partial + (size_t)(b * 16 + i) * HH + t;
    float c = mt[i] * inv;
    a0 += c * pp[0]; a1 += c * pp[256]; a2 += c * pp[512];
  }
  q2n[b * HH + t] = a0;
  q2n[b * HH + t + 256] = a1;
  q2n[b * HH + t + 512] = a2;
}

// K3: GEMM2 (swapped: D[h][n]) + all four output chunks.
// Grid: (b, tile, hc) = 32*16*6 = 3072 blocks; plain stores (L2 write-combine).
__global__ __launch_bounds__(256) void k_out(
    const float* __restrict__ nc, const unsigned short* __restrict__ qcT,
    const unsigned short* __restrict__ probs, const float* __restrict__ q2n,
    float* __restrict__ out)
{
  __shared__ char smem[16384];   // qcT chunk [128 h][64 q] bf16, XOR-swizzled

  const int tid = threadIdx.x;
  const int wv_ = tid >> 6, l = tid & 63;
  const int l15 = l & 15, lg = l >> 4;
  const int bid = blockIdx.x;
  const int hc = bid % 6;
  const int bt = bid / 6;              // b*16 + tile
  const int b = bt >> 4, tile = bt & 15;
  const int row0 = tile * 64;

  // A-frags (probs, pre-normalized bf16) direct from global (L2-hot)
  const unsigned short* pT = probs + (size_t)bt * (QQ * QQ);
  short8 a2[2];
  a2[0] = *(const short8*)((const char*)pT + (wv_ * 16 + l15) * 128 + 0 * 64 + lg * 16);
  a2[1] = *(const short8*)((const char*)pT + (wv_ * 16 + l15) * 128 + 1 * 64 + lg * 16);

  const unsigned short* qcTb = qcT + (size_t)b * HH * QQ;
  const int n = wv_ * 16 + l15;
  const float* ncrow = nc + (size_t)(b * NN + row0 + n) * HH;
  float* orow = out + (size_t)(b * NN + row0 + n) * 3072;
  const float* q2nb = q2n + b * HH;

#pragma unroll
  for (int i = 0; i < 4; ++i) {
    int unit = i * 256 + tid;     // 1024 units: 128 h-rows x 8
    int r = unit >> 3, uu = unit & 7;
    short8 v = *(const short8*)(qcTb + (size_t)(hc * 128 + r) * 64 + uu * 8);
    int off = r * 128 + ((uu * 16) ^ ((r & 7) << 4));
    *(short8*)(smem + off) = v;
  }
  __syncthreads();
#pragma unroll
  for (int hg = 0; hg < 8; ++hg) {
    f32x4 c2 = {};
#pragma unroll
    for (int ks2 = 0; ks2 < 2; ++ks2) {
      int hrow = hg * 16 + l15;
      int kbyte = ks2 * 64 + lg * 16;
      short8 hf = *(short8*)(smem + hrow * 128 + (kbyte ^ ((l & 7) << 4)));
      c2 = __builtin_amdgcn_mfma_f32_16x16x32_bf16(hf, a2[ks2], c2, 0, 0, 0);
    }
    // thread owns n = wv_*16+l15, h = hc*128 + hg*16 + lg*4 + (0..3)
    int hbase = hc * 128 + hg * 16 + lg * 4;
    f32x4 ncv = *(const f32x4*)(ncrow + hbase);
    f32x4 qv  = *(const f32x4*)(q2nb + hbase);
    *(f32x4*)(orow + hbase)            = ncv;
    *(f32x4*)(orow + HH + hbase)       = c2;
    *(f32x4*)(orow + 2 * HH + hbase)   = ncv * c2;
    *(f32x4*)(orow + 2304 + hbase)     = ncv * qv;
  }
}

extern "C" void kernel_launch(void* const* d_in, const int* in_sizes, int n_in,
                              void* d_out, int out_size, void* d_ws, size_t ws_size,
                              hipStream_t stream) {
  (void)in_sizes; (void)n_in; (void)out_size; (void)ws_size;
  const float* nc = (const float*)d_in[0];
  const float* qc = (const float*)d_in[1];
  const float* w  = (const float*)d_in[3];
  float* out = (float*)d_out;
  char* ws = (char*)d_ws;
  unsigned short* qcT = (unsigned short*)(ws);                 // 3,145,728 B
  float* sqv     = (float*)(ws + 3145728);                     // 8 KB
  float* partial = (float*)(ws + 3153920);                     // 1,572,864 B
  float* mtse    = (float*)(ws + 4726784);                     // 4 KB
  float* q2n     = (float*)(ws + 4730880);                     // 96 KB
  unsigned short* probs = (unsigned short*)(ws + 4829184);     // 4,194,304 B

  k_prep<<<6656, 256, 0, stream>>>(qc, w, qcT, sqv);
  k_sim<<<512, 256, 0, stream>>>(nc, qc, w, sqv, partial, mtse, probs);
  k_comb<<<32, 256, 0, stream>>>(partial, mtse, q2n);
  k_out<<<3072, 256, 0, stream>>>(nc, qcT, probs, q2n, out);
}

// Round 5
// 170.119 us; speedup vs baseline: 1.4530x; 1.0544x over previous
//
#include <hip/hip_runtime.h>
#include <hip/hip_bf16.h>

#define BB 32
#define NN 1024
#define QQ 64
#define HH 768

typedef __attribute__((ext_vector_type(8))) short short8;
typedef __attribute__((ext_vector_type(4))) float f32x4;

#define GLOAD_LDS16(gp, lp) \
  __builtin_amdgcn_global_load_lds((const __attribute__((address_space(1))) unsigned int*)(gp), \
                                   (__attribute__((address_space(3))) unsigned int*)(lp), 16, 0, 0)

__device__ __forceinline__ unsigned short f2b(float f) {
  unsigned int u = __float_as_uint(f);
  unsigned int r = u + 0x7fffu + ((u >> 16) & 1u);
  return (unsigned short)(r >> 16);
}

// K0: [0,768): qwB_sw = bf16(qc*w_nq + w_n), pre-XOR-swizzled [b][kc][q][16 units]
//     [768,1536): qcT_sw = bf16(qc^T), pre-XOR-swizzled [b][hc][128 h][8 units]
//     [1536,2048): sq[b][q] = dot(qc[b][q][:], w_q)
__global__ void k_prep(const float* __restrict__ qc, const float* __restrict__ w,
                       unsigned short* __restrict__ qwB, unsigned short* __restrict__ qcT,
                       float* __restrict__ sq) {
  const int bid = blockIdx.x, tid = threadIdx.x;
  if (bid < 768) {
    int gid = bid * 256 + tid;            // 16B-unit id, 0..196607
    int b = gid / 6144, rem = gid % 6144;
    int q = rem / 96, kk = rem % 96;      // kk: 8-elem unit within H
    int kc = kk >> 4, uu = kk & 15;
    const float* src = qc + ((size_t)(b * 64 + q) * HH + kk * 8);
    float4 g0 = *(const float4*)src, g1 = *(const float4*)(src + 4);
    int h = kk * 8;
    float4 n0 = *(const float4*)(w + h), n1 = *(const float4*)(w + h + 4);
    float4 m0 = *(const float4*)(w + 2 * HH + h), m1 = *(const float4*)(w + 2 * HH + h + 4);
    short8 v;
    v[0] = (short)f2b(g0.x * m0.x + n0.x); v[1] = (short)f2b(g0.y * m0.y + n0.y);
    v[2] = (short)f2b(g0.z * m0.z + n0.z); v[3] = (short)f2b(g0.w * m0.w + n0.w);
    v[4] = (short)f2b(g1.x * m1.x + n1.x); v[5] = (short)f2b(g1.y * m1.y + n1.y);
    v[6] = (short)f2b(g1.z * m1.z + n1.z); v[7] = (short)f2b(g1.w * m1.w + n1.w);
    size_t du = (size_t)(b * 6 + kc) * 1024 + q * 16 + (uu ^ (q & 7));
    *(short8*)((char*)qwB + du * 16) = v;
  } else if (bid < 1536) {
    int gid = (bid - 768) * 256 + tid;    // dest unit id (linear store, gathered load)
    int b = gid / 6144, p = gid % 6144;
    int hc = p >> 10, pr = p & 1023, r = pr >> 3, x = pr & 7;
    int xu = x ^ (r & 7);
    int h = hc * 128 + r;
    const float* col = qc + ((size_t)(b * 64 + xu * 8) * HH + h);
    short8 v;
#pragma unroll
    for (int j = 0; j < 8; ++j) v[j] = (short)f2b(col[(size_t)j * HH]);
    *(short8*)((char*)qcT + (size_t)gid * 16) = v;
  } else {
    int wid = ((bid - 1536) * 256 + tid) >> 6; // 0..2047 (b*64+q)
    int l = tid & 63;
    const float* row = qc + (size_t)wid * HH;
    float s = 0.f;
#pragma unroll
    for (int i = 0; i < 12; ++i) s += row[i * 64 + l] * w[HH + i * 64 + l];
#pragma unroll
    for (int m = 1; m < 64; m <<= 1) s += __shfl_xor(s, m);
    if (l == 0) sq[wid] = s;
  }
}

// K1: GEMM1 (sim) pipelined: A global->reg (prefetched), B' global_load_lds dbuf,
//     counted vmcnt; then softmax -> probs(bf16) + per-tile q2n partials.
__global__ __launch_bounds__(256) void k_sim(
    const float* __restrict__ nc, const unsigned short* __restrict__ qwB,
    const float* __restrict__ sq, float* __restrict__ partial,
    float* __restrict__ mtse, unsigned short* __restrict__ probs)
{
  __shared__ __align__(16) char bbuf[2][16384];
  __shared__ float rowmF[64];
  __shared__ float wvF[64];

  const int tid = threadIdx.x;
  const int wv_ = tid >> 6, l = tid & 63;
  const int l15 = l & 15, lg = l >> 4;
  const int b = blockIdx.x >> 4, tile = blockIdx.x & 15;
  const int row0 = tile * 64;

  const float* ncB = nc + (size_t)(b * NN + row0) * HH;
  const char* qwb = (const char*)qwB + (size_t)b * 98304;   // 6*16384
  const float* aBase = ncB + (wv_ * 16 + l15) * HH + lg * 8;

  // ---- prologue: B'(0) -> buf0, A(0) -> fr[0] ----
  {
    const char* gsrc = qwb + wv_ * 4096 + l * 16;
#pragma unroll
    for (int i = 0; i < 4; ++i)
      GLOAD_LDS16(gsrc + i * 1024, &bbuf[0][wv_ * 4096 + i * 1024]);
  }
  float4 fr[2][8];
#pragma unroll
  for (int ks = 0; ks < 4; ++ks) {
    fr[0][ks * 2]     = *(const float4*)(aBase + ks * 32);
    fr[0][ks * 2 + 1] = *(const float4*)(aBase + ks * 32 + 4);
  }

  f32x4 acc[4] = {};
#pragma unroll
  for (int kc = 0; kc < 6; ++kc) {
    // convert this phase's A (compiler waits only the A-load group)
    short8 af[4];
#pragma unroll
    for (int ks = 0; ks < 4; ++ks) {
      float4 f0 = fr[kc & 1][ks * 2], f1 = fr[kc & 1][ks * 2 + 1];
      short8 v;
      v[0] = (short)f2b(f0.x); v[1] = (short)f2b(f0.y);
      v[2] = (short)f2b(f0.z); v[3] = (short)f2b(f0.w);
      v[4] = (short)f2b(f1.x); v[5] = (short)f2b(f1.y);
      v[6] = (short)f2b(f1.z); v[7] = (short)f2b(f1.w);
      af[ks] = v;
    }
    if (kc < 5) {
      // prefetch next A (8 loads) + issue next B' (4 global_load_lds) = 12 vmem ops
#pragma unroll
      for (int ks = 0; ks < 4; ++ks) {
        fr[(kc + 1) & 1][ks * 2]     = *(const float4*)(aBase + (kc + 1) * 128 + ks * 32);
        fr[(kc + 1) & 1][ks * 2 + 1] = *(const float4*)(aBase + (kc + 1) * 128 + ks * 32 + 4);
      }
      const char* gsrc = qwb + (kc + 1) * 16384 + wv_ * 4096 + l * 16;
#pragma unroll
      for (int i = 0; i < 4; ++i)
        GLOAD_LDS16(gsrc + i * 1024, &bbuf[(kc + 1) & 1][wv_ * 4096 + i * 1024]);
      asm volatile("s_waitcnt vmcnt(12)" ::: "memory");  // drain B'(kc); keep 12 prefetches in flight
    } else {
      asm volatile("s_waitcnt vmcnt(0)" ::: "memory");
    }
    __builtin_amdgcn_s_barrier();
    __builtin_amdgcn_sched_barrier(0);
#pragma unroll
    for (int ks = 0; ks < 4; ++ks) {
      int kbyte = ks * 64 + lg * 16;
#pragma unroll
      for (int nt = 0; nt < 4; ++nt) {
        int brow = nt * 16 + l15;
        short8 bf = *(short8*)(&bbuf[kc & 1][0] + brow * 256 + (kbyte ^ ((l & 7) << 4)));
        acc[nt] = __builtin_amdgcn_mfma_f32_16x16x32_bf16(af[ks], bf, acc[nt], 0, 0, 0);
      }
    }
    __builtin_amdgcn_sched_barrier(0);
    __builtin_amdgcn_s_barrier();
  }

  // ---- softmax over q; D layout: row n = wv_*16+lg*4+j, col q = nt*16+l15 ----
  unsigned short* pT = probs + (size_t)(b * 16 + tile) * (QQ * QQ);
  float sqv[4];
#pragma unroll
  for (int nt = 0; nt < 4; ++nt) sqv[nt] = sq[b * QQ + nt * 16 + l15];
#pragma unroll
  for (int j = 0; j < 4; ++j) {
    float mm = -1e30f;
#pragma unroll
    for (int nt = 0; nt < 4; ++nt) { acc[nt][j] += sqv[nt]; mm = fmaxf(mm, acc[nt][j]); }
    mm = fmaxf(mm, __shfl_xor(mm, 1));
    mm = fmaxf(mm, __shfl_xor(mm, 2));
    mm = fmaxf(mm, __shfl_xor(mm, 4));
    mm = fmaxf(mm, __shfl_xor(mm, 8));
    float ss = 0.f;
#pragma unroll
    for (int nt = 0; nt < 4; ++nt) { float p = __expf(acc[nt][j] - mm); acc[nt][j] = p; ss += p; }
    ss += __shfl_xor(ss, 1); ss += __shfl_xor(ss, 2);
    ss += __shfl_xor(ss, 4); ss += __shfl_xor(ss, 8);
    float inv = 1.0f / ss;
    int r = wv_ * 16 + lg * 4 + j;
#pragma unroll
    for (int nt = 0; nt < 4; ++nt)
      pT[r * 64 + nt * 16 + l15] = f2b(acc[nt][j] * inv);
    if (l15 == 0) rowmF[r] = mm;
  }
  __syncthreads();

  // ---- per-tile q2n partials ----
  float m_t = -1e30f;
#pragma unroll
  for (int i = 0; i < 16; ++i) {
    f32x4 v = ((f32x4*)rowmF)[i];
    m_t = fmaxf(m_t, fmaxf(fmaxf(v[0], v[1]), fmaxf(v[2], v[3])));
  }
  if (tid < 64) wvF[tid] = __expf(rowmF[tid] - m_t);
  __syncthreads();
  {
    float sv = wvF[l];
#pragma unroll
    for (int m = 1; m < 64; m <<= 1) sv += __shfl_xor(sv, m);
    if (tid == 0) {
      mtse[(b * 16 + tile) * 2] = m_t;
      mtse[(b * 16 + tile) * 2 + 1] = sv;
    }
  }
  {
    float p0 = 0.f, p1 = 0.f, p2 = 0.f;
    for (int n = 0; n < 64; ++n) {
      float wvv = wvF[n];
      const float* pr = ncB + n * HH + tid;
      p0 += wvv * pr[0]; p1 += wvv * pr[256]; p2 += wvv * pr[512];
    }
    float* pp = partial + (size_t)(b * 16 + tile) * HH + tid;
    pp[0] = p0; pp[256] = p1; pp[512] = p2;
  }
}

// K2: GEMM2 (swapped: D[h][n]) + q2n combine (folded) + all four output chunks.
// Grid: (b, tile, hc) = 3072 blocks.
__global__ __launch_bounds__(256) void k_out(
    const float* __restrict__ nc, const unsigned short* __restrict__ qcT,
    const unsigned short* __restrict__ probs, const float* __restrict__ partial,
    const float* __restrict__ mtse, float* __restrict__ out)
{
  __shared__ __align__(16) char smem[16384];   // qcT chunk [128 h][8 units], pre-swizzled
  __shared__ float q2nL[128];

  const int tid = threadIdx.x;
  const int wv_ = tid >> 6, l = tid & 63;
  const int l15 = l & 15, lg = l >> 4;
  const int bid = blockIdx.x;
  const int hc = bid % 6;
  const int bt = bid / 6;              // b*16 + tile
  const int b = bt >> 4, tile = bt & 15;
  const int row0 = tile * 64;

  // stage qcT chunk via async direct-to-LDS (source pre-swizzled)
  {
    const char* src = (const char*)qcT + ((size_t)(b * 6 + hc) << 14) + wv_ * 4096 + l * 16;
#pragma unroll
    for (int i = 0; i < 4; ++i)
      GLOAD_LDS16(src + i * 1024, &smem[wv_ * 4096 + i * 1024]);
  }

  // q2n slice for this h-chunk (replaces k_comb)
  if (tid < 128) {
    float M = -1e30f, mt[16], se[16];
#pragma unroll
    for (int i = 0; i < 16; ++i) {
      mt[i] = mtse[(b * 16 + i) * 2];
      se[i] = mtse[(b * 16 + i) * 2 + 1];
      M = fmaxf(M, mt[i]);
    }
    float denom = 0.f;
#pragma unroll
    for (int i = 0; i < 16; ++i) { mt[i] = __expf(mt[i] - M); denom += mt[i] * se[i]; }
    float inv = 1.0f / denom;
    float a = 0.f;
#pragma unroll
    for (int i = 0; i < 16; ++i)
      a += mt[i] * partial[(size_t)(b * 16 + i) * HH + hc * 128 + tid];
    q2nL[tid] = a * inv;
  }

  // probs A-frags (pre-normalized bf16), direct from global (L2-hot)
  const unsigned short* pT = probs + (size_t)bt * (QQ * QQ);
  short8 a2_0 = *(const short8*)((const char*)pT + (wv_ * 16 + l15) * 128 + lg * 16);
  short8 a2_1 = *(const short8*)((const char*)pT + (wv_ * 16 + l15) * 128 + 64 + lg * 16);

  asm volatile("s_waitcnt vmcnt(0)" ::: "memory");
  __syncthreads();

  const int n = wv_ * 16 + l15;
  const float* ncrow = nc + (size_t)(b * NN + row0 + n) * HH;
  float* orow = out + (size_t)(b * NN + row0 + n) * 3072;

#pragma unroll
  for (int hg = 0; hg < 8; ++hg) {
    f32x4 c2 = {};
#pragma unroll
    for (int ks2 = 0; ks2 < 2; ++ks2) {
      int hrow = hg * 16 + l15;
      int kbyte = ks2 * 64 + lg * 16;
      short8 hf = *(short8*)(&smem[0] + hrow * 128 + (kbyte ^ ((l & 7) << 4)));
      c2 = __builtin_amdgcn_mfma_f32_16x16x32_bf16(hf, ks2 ? a2_1 : a2_0, c2, 0, 0, 0);
    }
    // thread owns n, h = hc*128 + hg*16 + lg*4 + (0..3)
    int hl = hg * 16 + lg * 4;
    int hbase = hc * 128 + hl;
    f32x4 ncv = *(const f32x4*)(ncrow + hbase);
    f32x4 qv  = *(const f32x4*)(&q2nL[hl]);
    *(f32x4*)(orow + hbase)          = ncv;
    *(f32x4*)(orow + HH + hbase)     = c2;
    *(f32x4*)(orow + 2 * HH + hbase) = ncv * c2;
    *(f32x4*)(orow + 2304 + hbase)   = ncv * qv;
  }
}

extern "C" void kernel_launch(void* const* d_in, const int* in_sizes, int n_in,
                              void* d_out, int out_size, void* d_ws, size_t ws_size,
                              hipStream_t stream) {
  (void)in_sizes; (void)n_in; (void)out_size; (void)ws_size;
  const float* nc = (const float*)d_in[0];
  const float* qc = (const float*)d_in[1];
  const float* w  = (const float*)d_in[3];
  float* out = (float*)d_out;
  char* ws = (char*)d_ws;
  unsigned short* qwB = (unsigned short*)(ws);                 // 3,145,728 B (pre-swizzled)
  unsigned short* qcT = (unsigned short*)(ws + 3145728);       // 3,145,728 B (pre-swizzled)
  float* sqv     = (float*)(ws + 6291456);                     // 8 KB
  float* partial = (float*)(ws + 6299648);                     // 1,572,864 B
  float* mtse    = (float*)(ws + 7872512);                     // 4 KB
  unsigned short* probs = (unsigned short*)(ws + 7876608);     // 4,194,304 B

  k_prep<<<2048, 256, 0, stream>>>(qc, w, qwB, qcT, sqv);
  k_sim<<<512, 256, 0, stream>>>(nc, qwB, sqv, partial, mtse, probs);
  k_out<<<3072, 256, 0, stream>>>(nc, qcT, probs, partial, mtse, out);
}